// Round 4
// baseline (1622.708 us; speedup 1.0000x reference)
//
#include <hip/hip_runtime.h>

#define EPSF 1e-5f

typedef __attribute__((ext_vector_type(8))) short short8;
typedef __attribute__((ext_vector_type(4))) float f32x4;

__device__ __forceinline__ ushort f2bf(float x) {
    union { float f; unsigned u; } c; c.f = x;
    unsigned r = c.u + 0x7FFF + ((c.u >> 16) & 1);   // RNE
    return (ushort)(r >> 16);
}
__device__ __forceinline__ float bf2f(ushort b) {
    union { unsigned u; float f; } c; c.u = ((unsigned)b) << 16;
    return c.f;
}

// ---------------------------------------------------------------------------
// Geometry: B=1, C=32, H=96, W=128, L=2, N=7 (49 displacements)
// Activations: NHWC bf16 with 1-px zero halo: [d][H+2][W+2][C]
//   x0 [98][130][64]  x1 [98][130][96]  x2 [50][66][128]
//   x3 [50][66][128]  x4 [50][66][64]   x5 [98][130][32]
// Weights: [tap][COUT][CIN] bf16 (repacked); ctw5: [parity][tap][32][64]
// ---------------------------------------------------------------------------

__global__ __launch_bounds__(256) void k_repack_conv(
    const float* __restrict__ src, ushort* __restrict__ dst, int CO, int CI)
{
    int idx = blockIdx.x * 256 + threadIdx.x;
    if (idx >= CO * CI * 9) return;
    int co = idx / (CI * 9);
    int rem = idx % (CI * 9);
    int ci = rem / 9, tap = rem % 9;
    dst[((size_t)tap * CO + co) * CI + ci] = f2bf(src[idx]);
}

__global__ __launch_bounds__(256) void k_repack_ct(
    const float* __restrict__ src, ushort* __restrict__ dst)
{
    int idx = blockIdx.x * 256 + threadIdx.x;
    if (idx >= 4 * 4 * 32 * 64) return;
    int ci = idx & 63;
    int t = idx >> 6;
    int co = t & 31; t >>= 5;
    int tap = t & 3;
    int parity = t >> 2;
    int ph = parity >> 1, pw = parity & 1;
    int a = tap >> 1, b = tap & 1;
    int kh = ((ph + 1) & 1) + 2 * a;
    int kw = ((pw + 1) & 1) + 2 * b;
    dst[idx] = f2bf(src[((ci * 32 + co) * 4 + kh) * 4 + kw]);
}

// zero halo cells of a padded [DC][PH][PW][CH] buffer
__global__ __launch_bounds__(256) void k_zero_pads(
    ushort* __restrict__ buf, int PH, int PW, int CH)
{
    const int r = blockIdx.x, d = blockIdx.y;
    ushort* row = buf + ((size_t)d * PH + r) * PW * CH;
    if (r == 0 || r == PH - 1) {
        for (int i = threadIdx.x; i < PW * CH; i += 256) row[i] = 0;
    } else {
        for (int i = threadIdx.x; i < 2 * CH; i += 256) {
            int c = (i < CH) ? i : ((PW - 1) * CH + (i - CH));
            row[c] = 0;
        }
    }
}

// ---------------- sample + concat -> x0 padded [98][130][64] ---------------
__global__ __launch_bounds__(256) void k_sample_nhwc(
    const float* __restrict__ f1, const float* __restrict__ f2,
    const float* __restrict__ coords, ushort* __restrict__ x0,
    int d0, float inv_scale)
{
    const int HW = 96 * 128;
    const int sp = blockIdx.x * 256 + threadIdx.x;
    const int dd = blockIdx.z;
    const int d = d0 + dd;
    const int du = d / 7, dv = d % 7;

    float cx = coords[sp] * inv_scale + (float)(du - 3);
    float cy = coords[HW + sp] * inv_scale + (float)(dv - 3);
    float xf = floorf(cx), yf = floorf(cy);
    float wx = cx - xf, wy = cy - yf;
    int xi = (int)xf, yi = (int)yf;
    float vx0 = (xf >= 0.f && xf <= 127.f) ? 1.f : 0.f;
    float vx1 = (xf + 1.f >= 0.f && xf + 1.f <= 127.f) ? 1.f : 0.f;
    float vy0 = (yf >= 0.f && yf <= 95.f) ? 1.f : 0.f;
    float vy1 = (yf + 1.f >= 0.f && yf + 1.f <= 95.f) ? 1.f : 0.f;
    int x0i = min(max(xi, 0), 127), x1i = min(max(xi + 1, 0), 127);
    int y0i = min(max(yi, 0), 95),  y1i = min(max(yi + 1, 0), 95);
    float w00 = (1.f - wx) * (1.f - wy) * vx0 * vy0;
    float w01 = wx * (1.f - wy) * vx1 * vy0;
    float w10 = (1.f - wx) * wy * vx0 * vy1;
    float w11 = wx * wy * vx1 * vy1;
    int o00 = y0i * 128 + x0i, o01 = y0i * 128 + x1i;
    int o10 = y1i * 128 + x0i, o11 = y1i * 128 + x1i;

    const int r = sp >> 7, c = sp & 127;
    ushort* dst = x0 + ((size_t)dd * 98 * 130 + (size_t)(r + 1) * 130 + (c + 1)) * 64;
    #pragma unroll
    for (int g = 0; g < 4; ++g) {               // f1 channels 0..31
        uint4 pk;
        uint* pw_ = (uint*)&pk;
        #pragma unroll
        for (int q = 0; q < 4; ++q) {
            int cc = g * 8 + q * 2;
            pw_[q] = (uint)f2bf(f1[(size_t)cc * HW + sp])
                   | ((uint)f2bf(f1[(size_t)(cc + 1) * HW + sp]) << 16);
        }
        *(uint4*)(dst + g * 8) = pk;
    }
    #pragma unroll
    for (int g = 0; g < 4; ++g) {               // sampled f2 channels 32..63
        uint4 pk;
        uint* pw_ = (uint*)&pk;
        #pragma unroll
        for (int q = 0; q < 4; ++q) {
            uint wv = 0;
            #pragma unroll
            for (int h = 0; h < 2; ++h) {
                int cc = g * 8 + q * 2 + h;
                const float* fc = f2 + (size_t)cc * HW;
                float s = w00 * fc[o00] + w01 * fc[o01] + w10 * fc[o10] + w11 * fc[o11];
                wv |= ((uint)f2bf(s)) << (16 * h);
            }
            pw_[q] = wv;
        }
        *(uint4*)(dst + 32 + g * 8) = pk;
    }
}

// ---------------- LDS-tiled conv3x3 stride-1 (+BN+ReLU) --------------------
// Block: 256 thr = 4 waves; out tile 4 rows x 64 cols (wave = 1 row).
// LDS tile: 6 rows x 66 cols x 64ch chunk, XOR-swizzled, 49.5 KB.
template <int CIN, int COUT, int IH, int IW>
__global__ __launch_bounds__(256, 2) void k_conv3x3_lds(
    const ushort* __restrict__ in, ushort* __restrict__ out,
    const ushort* __restrict__ w,
    const float* __restrict__ bs, const float* __restrict__ bb,
    const float* __restrict__ bm, const float* __restrict__ bv)
{
    constexpr int IWP = IW + 2;
    constexpr int NCT = IW / 64;
    constexpr int NCH = CIN / 64;
    constexpr int NF = COUT / 16;
    constexpr int CINB = CIN * 2;
    constexpr int TB = 6 * 66 * 128;        // tile bytes
    __shared__ ushort smem[6 * 66 * 64];

    const int tid = threadIdx.x;
    const int lane = tid & 63, wid = tid >> 6;
    const int lr = lane & 15, kg = lane >> 4;
    const int d = blockIdx.z;
    const int r0 = (blockIdx.x / NCT) * 4;
    const int c0 = (blockIdx.x % NCT) * 64;

    const ushort* ib = in + (size_t)d * (IH + 2) * IWP * CIN;
    const char* gb0 = (const char*)(ib + ((size_t)r0 * IWP + c0) * CIN);

    f32x4 acc[4][NF];
    #pragma unroll
    for (int mf = 0; mf < 4; ++mf)
        #pragma unroll
        for (int nf = 0; nf < NF; ++nf)
            acc[mf][nf] = (f32x4){0.f, 0.f, 0.f, 0.f};

    #pragma unroll 1
    for (int ch = 0; ch < NCH; ++ch) {
        if (ch) __syncthreads();
        // ---- stage (reg-staged, swizzled writes) ----
        const char* gb = gb0 + ch * 128;
        #pragma unroll
        for (int rd = 0; rd < 13; ++rd) {
            int la = (rd * 256 + tid) * 16;
            if (la < TB) {
                int sp = la >> 7;
                int off = la & 127;
                int trow = sp / 66, tcol = sp - trow * 66;
                short8 v = *(const short8*)(gb + ((size_t)trow * IWP + tcol) * CINB + off);
                *(short8*)((char*)smem + (la ^ ((sp & 7) << 4))) = v;
            }
        }
        __syncthreads();

        // ---- 9 taps, A from LDS, B from global (L1/L2-hot) ----
        #pragma unroll
        for (int kh = 0; kh < 3; ++kh) {
            #pragma unroll
            for (int kw = 0; kw < 3; ++kw) {
                const ushort* wt = w + (size_t)(kh * 3 + kw) * COUT * CIN + ch * 64;
                short8 a[4][2];
                #pragma unroll
                for (int mf = 0; mf < 4; ++mf) {
                    int sp = (wid + kh) * 66 + mf * 16 + lr + kw;
                    int base = sp * 128;
                    int key = (sp & 7) << 4;
                    a[mf][0] = *(const short8*)((const char*)smem + base + ((kg * 16) ^ key));
                    a[mf][1] = *(const short8*)((const char*)smem + base + ((64 + kg * 16) ^ key));
                }
                #pragma unroll
                for (int nf = 0; nf < NF; ++nf) {
                    const ushort* wp = wt + (size_t)(nf * 16 + lr) * CIN + kg * 8;
                    short8 b0 = *(const short8*)(wp);
                    short8 b1 = *(const short8*)(wp + 32);
                    #pragma unroll
                    for (int mf = 0; mf < 4; ++mf) {
                        acc[mf][nf] = __builtin_amdgcn_mfma_f32_16x16x32_bf16(a[mf][0], b0, acc[mf][nf], 0, 0, 0);
                        acc[mf][nf] = __builtin_amdgcn_mfma_f32_16x16x32_bf16(a[mf][1], b1, acc[mf][nf], 0, 0, 0);
                    }
                }
            }
        }
    }

    // ---- epilogue: BN+ReLU, padded NHWC write ----
    ushort* ob = out + (size_t)d * (IH + 2) * IWP * COUT;
    const int r_out = r0 + wid;
    #pragma unroll
    for (int nf = 0; nf < NF; ++nf) {
        const int col = nf * 16 + lr;
        const float inv = bs[col] * rsqrtf(bv[col] + EPSF);
        const float beta = bb[col] - bm[col] * inv;
        #pragma unroll
        for (int mf = 0; mf < 4; ++mf) {
            #pragma unroll
            for (int j = 0; j < 4; ++j) {
                int c_out = c0 + mf * 16 + kg * 4 + j;
                float y = fmaxf(fmaf(acc[mf][nf][j], inv, beta), 0.f);
                ob[((size_t)(r_out + 1) * IWP + (c_out + 1)) * COUT + col] = f2bf(y);
            }
        }
    }
}

// ---------------- conv2: 3x3 stride-2, direct global (padded, maskless) ----
// in x1 [98][130][96] -> out x2 [50][66][128]
__global__ __launch_bounds__(256) void k_conv2_global(
    const ushort* __restrict__ in, ushort* __restrict__ out,
    const ushort* __restrict__ w,
    const float* __restrict__ bs, const float* __restrict__ bb,
    const float* __restrict__ bm, const float* __restrict__ bv)
{
    const int lane = threadIdx.x & 63, wid = threadIdx.x >> 6;
    const int m0 = blockIdx.x * 256 + wid * 64;
    const int d = blockIdx.z;
    const int lr = lane & 15, kg = lane >> 4;

    int srcoff[4];
    #pragma unroll
    for (int mf = 0; mf < 4; ++mf) {
        int m = m0 + mf * 16 + lr;
        int oh = m >> 6, ow = m & 63;
        srcoff[mf] = (2 * oh * 130 + 2 * ow) * 96;
    }

    f32x4 acc[4][8];
    #pragma unroll
    for (int mf = 0; mf < 4; ++mf)
        #pragma unroll
        for (int nf = 0; nf < 8; ++nf)
            acc[mf][nf] = (f32x4){0.f, 0.f, 0.f, 0.f};

    const ushort* ib = in + (size_t)d * 98 * 130 * 96;

    for (int kh = 0; kh < 3; ++kh) {
        for (int kw = 0; kw < 3; ++kw) {
            const int toff = (kh * 130 + kw) * 96;
            const ushort* wt = w + (size_t)(kh * 3 + kw) * 128 * 96;
            #pragma unroll
            for (int cc = 0; cc < 3; ++cc) {
                const int kbase = cc * 32 + kg * 8;
                short8 a[4];
                #pragma unroll
                for (int mf = 0; mf < 4; ++mf)
                    a[mf] = *(const short8*)(ib + srcoff[mf] + toff + kbase);
                #pragma unroll
                for (int nf = 0; nf < 8; ++nf) {
                    short8 bfr = *(const short8*)(wt + (size_t)(nf * 16 + lr) * 96 + kbase);
                    #pragma unroll
                    for (int mf = 0; mf < 4; ++mf)
                        acc[mf][nf] = __builtin_amdgcn_mfma_f32_16x16x32_bf16(
                            a[mf], bfr, acc[mf][nf], 0, 0, 0);
                }
            }
        }
    }

    ushort* ob = out + (size_t)d * 50 * 66 * 128;
    #pragma unroll
    for (int nf = 0; nf < 8; ++nf) {
        const int col = nf * 16 + lr;
        const float inv = bs[col] * rsqrtf(bv[col] + EPSF);
        const float beta = bb[col] - bm[col] * inv;
        #pragma unroll
        for (int mf = 0; mf < 4; ++mf) {
            #pragma unroll
            for (int j = 0; j < 4; ++j) {
                int m = m0 + mf * 16 + kg * 4 + j;
                int oh = m >> 6, ow = m & 63;
                float y = fmaxf(fmaf(acc[mf][nf][j], inv, beta), 0.f);
                ob[((size_t)(oh + 1) * 66 + (ow + 1)) * 128 + col] = f2bf(y);
            }
        }
    }
}

// ---------------- LDS-tiled convT4x4 s2 (+BN+ReLU) -------------------------
// in x4 [50][66][64] -> out x5 [98][130][32]; w [parity][tap][32][64]
__global__ __launch_bounds__(256, 2) void k_convt_lds(
    const ushort* __restrict__ in, ushort* __restrict__ out,
    const ushort* __restrict__ w,
    const float* __restrict__ bs, const float* __restrict__ bb,
    const float* __restrict__ bm, const float* __restrict__ bv)
{
    constexpr int TB = 6 * 66 * 128;
    __shared__ ushort smem[6 * 66 * 64];
    const int tid = threadIdx.x;
    const int lane = tid & 63, wid = tid >> 6;
    const int lr = lane & 15, kg = lane >> 4;
    const int parity = blockIdx.y;
    const int ph = parity >> 1, pw = parity & 1;
    const int d = blockIdx.z;
    const int q0 = blockIdx.x * 4;

    const ushort* ib = in + (size_t)d * 50 * 66 * 64;
    const char* gb = (const char*)(ib + (size_t)q0 * 66 * 64);

    f32x4 acc[4][2];
    #pragma unroll
    for (int mf = 0; mf < 4; ++mf)
        #pragma unroll
        for (int nf = 0; nf < 2; ++nf)
            acc[mf][nf] = (f32x4){0.f, 0.f, 0.f, 0.f};

    // stage: rows q0-1..q0+4 (contiguous full-width region)
    #pragma unroll
    for (int rd = 0; rd < 13; ++rd) {
        int la = (rd * 256 + tid) * 16;
        if (la < TB) {
            int sp = la >> 7;
            short8 v = *(const short8*)(gb + la);
            *(short8*)((char*)smem + (la ^ ((sp & 7) << 4))) = v;
        }
    }
    __syncthreads();

    #pragma unroll
    for (int a = 0; a < 2; ++a) {
        #pragma unroll
        for (int b2 = 0; b2 < 2; ++b2) {
            const ushort* wt = w + (size_t)((parity * 4 + a * 2 + b2) * 32) * 64;
            short8 av[4][2];
            #pragma unroll
            for (int mf = 0; mf < 4; ++mf) {
                int tr = wid + ph + 1 - a;
                int tc = mf * 16 + lr + pw + 1 - b2;
                int sp = tr * 66 + tc;
                int base = sp * 128;
                int key = (sp & 7) << 4;
                av[mf][0] = *(const short8*)((const char*)smem + base + ((kg * 16) ^ key));
                av[mf][1] = *(const short8*)((const char*)smem + base + ((64 + kg * 16) ^ key));
            }
            #pragma unroll
            for (int nf = 0; nf < 2; ++nf) {
                const ushort* wp = wt + (size_t)(nf * 16 + lr) * 64 + kg * 8;
                short8 b0 = *(const short8*)(wp);
                short8 b1 = *(const short8*)(wp + 32);
                #pragma unroll
                for (int mf = 0; mf < 4; ++mf) {
                    acc[mf][nf] = __builtin_amdgcn_mfma_f32_16x16x32_bf16(av[mf][0], b0, acc[mf][nf], 0, 0, 0);
                    acc[mf][nf] = __builtin_amdgcn_mfma_f32_16x16x32_bf16(av[mf][1], b1, acc[mf][nf], 0, 0, 0);
                }
            }
        }
    }

    ushort* ob = out + (size_t)d * 98 * 130 * 32;
    const int q = q0 + wid;
    #pragma unroll
    for (int nf = 0; nf < 2; ++nf) {
        const int col = nf * 16 + lr;
        const float inv = bs[col] * rsqrtf(bv[col] + EPSF);
        const float beta = bb[col] - bm[col] * inv;
        #pragma unroll
        for (int mf = 0; mf < 4; ++mf) {
            #pragma unroll
            for (int j = 0; j < 4; ++j) {
                int cpg = mf * 16 + kg * 4 + j;
                float y = fmaxf(fmaf(acc[mf][nf][j], inv, beta), 0.f);
                ob[((size_t)(2 * q + ph + 1) * 130 + (2 * cpg + pw + 1)) * 32 + col] = f2bf(y);
            }
        }
    }
}

// ---------------- conv6 (32->1) + bias, padded in, fp32 out ----------------
__global__ __launch_bounds__(256) void k_conv6(
    const ushort* __restrict__ x5,    // [dc][98][130][32]
    float* __restrict__ cost,         // [49][12288]
    const float* __restrict__ w,      // [32][3][3]
    const float* __restrict__ biasp, int d0)
{
    const int sp = blockIdx.x * 256 + threadIdx.x;
    const int dd = blockIdx.z;
    const int oh = sp >> 7, ow = sp & 127;
    float acc = 0.f;
    #pragma unroll
    for (int kh = 0; kh < 3; ++kh) {
        #pragma unroll
        for (int kw = 0; kw < 3; ++kw) {
            const ushort* p = x5 + ((size_t)dd * 98 * 130
                                  + (size_t)(oh + kh) * 130 + (ow + kw)) * 32;
            const int tap = kh * 3 + kw;
            #pragma unroll
            for (int q = 0; q < 4; ++q) {
                uint4 v = *(const uint4*)(p + q * 8);
                const uint* vw = (const uint*)&v;
                #pragma unroll
                for (int t = 0; t < 4; ++t) {
                    int ci = q * 8 + t * 2;
                    acc = fmaf(bf2f((ushort)(vw[t] & 0xFFFF)), w[ci * 9 + tap], acc);
                    acc = fmaf(bf2f((ushort)(vw[t] >> 16)), w[(ci + 1) * 9 + tap], acc);
                }
            }
        }
    }
    cost[(size_t)(d0 + dd) * 12288 + sp] = acc + biasp[0];
}

// ---------------- DAP ------------------------------------------------------
__global__ __launch_bounds__(256) void k_dap(
    const float* __restrict__ cost, const float* __restrict__ dw,
    float* __restrict__ out)
{
    const int sp = blockIdx.x * 256 + threadIdx.x;
    const int p = blockIdx.y;
    const float* dr = dw + p * 49;
    float acc = 0.f;
    #pragma unroll
    for (int q = 0; q < 49; ++q)
        acc = fmaf(dr[q], cost[(size_t)q * 12288 + sp], acc);
    out[(size_t)p * 12288 + sp] = acc;
}

// ---------------------------------------------------------------------------
extern "C" void kernel_launch(void* const* d_in, const int* in_sizes, int n_in,
                              void* d_out, int out_size, void* d_ws, size_t ws_size,
                              hipStream_t stream)
{
    const float* fm1[2] = { (const float*)d_in[0], (const float*)d_in[2] };
    const float* fm2[2] = { (const float*)d_in[1], (const float*)d_in[3] };
    const float* coords = (const float*)d_in[4];
    const float* cw1  = (const float*)d_in[5];
    const float* cw2  = (const float*)d_in[6];
    const float* cw3  = (const float*)d_in[7];
    const float* cw4  = (const float*)d_in[8];
    const float* ctw5 = (const float*)d_in[9];
    const float* cw6  = (const float*)d_in[10];
    const float* cb6  = (const float*)d_in[11];
    const float* bn[5][4];
    for (int j = 0; j < 5; ++j)
        for (int k = 0; k < 4; ++k)
            bn[j][k] = (const float*)d_in[12 + j * 4 + k];
    const float* dap = (const float*)d_in[32];
    float* out = (float*)d_out;

    // per-d padded buffer sizes (ushorts)
    const size_t X0 = (size_t)98 * 130 * 64;
    const size_t X1 = (size_t)98 * 130 * 96;
    const size_t X2 = (size_t)50 * 66 * 128;
    const size_t X3 = (size_t)50 * 66 * 128;
    const size_t X4 = (size_t)50 * 66 * 64;
    const size_t X5 = (size_t)98 * 130 * 32;
    const size_t PERD = X0 + X1 + X2 + X3 + X4 + X5;
    const size_t W_US = 2 * (size_t)(9*96*64 + 9*128*96 + 9*128*128 + 9*64*128 + 16*32*64);
    const size_t COST_F = (size_t)49 * 12288;

    int DC = 1;
    for (int cand : {49, 25, 17, 13, 9, 7, 5, 3, 2, 1}) {
        size_t need = PERD * 2 * (size_t)cand + W_US * 2 + COST_F * 4 + 65536;
        if (need <= ws_size) { DC = cand; break; }
    }

    ushort* x0 = (ushort*)d_ws;
    ushort* x1 = x0 + X0 * DC;
    ushort* x2 = x1 + X1 * DC;
    ushort* x3 = x2 + X2 * DC;
    ushort* x4 = x3 + X3 * DC;
    ushort* x5 = x4 + X4 * DC;
    ushort* wp = x5 + X5 * DC;
    ushort* wr1[2], *wr2[2], *wr3[2], *wr4[2], *wr5[2];
    for (int l = 0; l < 2; ++l) {
        wr1[l] = wp; wp += 9 * 96 * 64;
        wr2[l] = wp; wp += 9 * 128 * 96;
        wr3[l] = wp; wp += 9 * 128 * 128;
        wr4[l] = wp; wp += 9 * 64 * 128;
        wr5[l] = wp; wp += 16 * 32 * 64;
    }
    float* cost = (float*)wp;

    // ---- weight repack ----
    for (int l = 0; l < 2; ++l) {
        k_repack_conv<<<dim3(216), 256, 0, stream>>>(cw1 + (size_t)l * 96 * 64 * 9,   wr1[l], 96, 64);
        k_repack_conv<<<dim3(432), 256, 0, stream>>>(cw2 + (size_t)l * 128 * 96 * 9,  wr2[l], 128, 96);
        k_repack_conv<<<dim3(576), 256, 0, stream>>>(cw3 + (size_t)l * 128 * 128 * 9, wr3[l], 128, 128);
        k_repack_conv<<<dim3(288), 256, 0, stream>>>(cw4 + (size_t)l * 64 * 128 * 9,  wr4[l], 64, 128);
        k_repack_ct<<<dim3(128), 256, 0, stream>>>(ctw5 + (size_t)l * 64 * 32 * 16, wr5[l]);
    }

    // ---- zero halos (once per call; interiors rewritten every chunk) ----
    k_zero_pads<<<dim3(98, DC), 256, 0, stream>>>(x0, 98, 130, 64);
    k_zero_pads<<<dim3(98, DC), 256, 0, stream>>>(x1, 98, 130, 96);
    k_zero_pads<<<dim3(50, DC), 256, 0, stream>>>(x2, 50, 66, 128);
    k_zero_pads<<<dim3(50, DC), 256, 0, stream>>>(x3, 50, 66, 128);
    k_zero_pads<<<dim3(50, DC), 256, 0, stream>>>(x4, 50, 66, 64);
    k_zero_pads<<<dim3(98, DC), 256, 0, stream>>>(x5, 98, 130, 32);

    for (int l = 0; l < 2; ++l) {
        const float inv_scale = l ? 0.5f : 1.0f;
        for (int d0 = 0; d0 < 49; d0 += DC) {
            const int dc = min(DC, 49 - d0);
            k_sample_nhwc<<<dim3(48, 1, dc), 256, 0, stream>>>(
                fm1[l], fm2[l], coords, x0, d0, inv_scale);
            k_conv3x3_lds<64, 96, 96, 128>
                <<<dim3(48, 1, dc), 256, 0, stream>>>(x0, x1, wr1[l],
                    bn[0][0] + l * 96,  bn[0][1] + l * 96,  bn[0][2] + l * 96,  bn[0][3] + l * 96);
            k_conv2_global<<<dim3(12, 1, dc), 256, 0, stream>>>(x1, x2, wr2[l],
                    bn[1][0] + l * 128, bn[1][1] + l * 128, bn[1][2] + l * 128, bn[1][3] + l * 128);
            k_conv3x3_lds<128, 128, 48, 64>
                <<<dim3(12, 1, dc), 256, 0, stream>>>(x2, x3, wr3[l],
                    bn[2][0] + l * 128, bn[2][1] + l * 128, bn[2][2] + l * 128, bn[2][3] + l * 128);
            k_conv3x3_lds<128, 64, 48, 64>
                <<<dim3(12, 1, dc), 256, 0, stream>>>(x3, x4, wr4[l],
                    bn[3][0] + l * 64,  bn[3][1] + l * 64,  bn[3][2] + l * 64,  bn[3][3] + l * 64);
            k_convt_lds<<<dim3(12, 4, dc), 256, 0, stream>>>(x4, x5, wr5[l],
                    bn[4][0] + l * 32,  bn[4][1] + l * 32,  bn[4][2] + l * 32,  bn[4][3] + l * 32);
            k_conv6<<<dim3(48, 1, dc), 256, 0, stream>>>(
                x5, cost, cw6 + (size_t)l * 32 * 9, cb6 + l, d0);
        }
        k_dap<<<dim3(48, 49), 256, 0, stream>>>(
            cost, dap + (size_t)l * 49 * 49, out + (size_t)l * 49 * 12288);
    }
}